// Round 1
// baseline (452.547 us; speedup 1.0000x reference)
//
#include <hip/hip_runtime.h>
#include <hip/hip_bf16.h>

typedef __attribute__((ext_vector_type(8))) __bf16 bf16x8;
typedef __attribute__((ext_vector_type(4))) float f32x4;

#define IN_CH 512
#define OUT_CH 64
#define WT_STRIDE 520  // 512 + 8 bf16 pad per row (row = one output channel)

// ---------------- GEMM: base = features @ W (bf16 MFMA, fp32 accum) ----------
__global__ __launch_bounds__(256) void gemm_kernel(
    const float* __restrict__ A,   // [N,512]
    const float* __restrict__ W,   // [512,64]
    float* __restrict__ out,       // [N,64]
    int N)
{
    __shared__ __align__(16) __bf16 Wt[OUT_CH * WT_STRIDE]; // Wt[n][k]

    const int tid = threadIdx.x;
    for (int idx = tid; idx < IN_CH * OUT_CH; idx += 256) {
        int k = idx >> 6, n = idx & 63;
        Wt[n * WT_STRIDE + k] = (__bf16)W[idx];
    }
    __syncthreads();

    const int lane = tid & 63;
    const int wave = tid >> 6;
    const int row0 = blockIdx.x * 64 + wave * 16;
    int row_a = row0 + (lane & 15);
    int row_c = row_a < N ? row_a : N - 1;   // clamp for loads

    const float* arow = A + (size_t)row_c * IN_CH;
    const int kg = (lane >> 4) * 8;          // k-offset within each 32-chunk
    const int col = lane & 15;

    f32x4 acc0 = {0.f,0.f,0.f,0.f}, acc1 = {0.f,0.f,0.f,0.f};
    f32x4 acc2 = {0.f,0.f,0.f,0.f}, acc3 = {0.f,0.f,0.f,0.f};

    for (int ks = 0; ks < IN_CH / 32; ++ks) {
        int kb = ks * 32 + kg;
        float4 p = *(const float4*)(arow + kb);
        float4 q = *(const float4*)(arow + kb + 4);
        bf16x8 a;
        a[0]=(__bf16)p.x; a[1]=(__bf16)p.y; a[2]=(__bf16)p.z; a[3]=(__bf16)p.w;
        a[4]=(__bf16)q.x; a[5]=(__bf16)q.y; a[6]=(__bf16)q.z; a[7]=(__bf16)q.w;
        bf16x8 b0 = *(const bf16x8*)(&Wt[(col     ) * WT_STRIDE + kb]);
        bf16x8 b1 = *(const bf16x8*)(&Wt[(col + 16) * WT_STRIDE + kb]);
        bf16x8 b2 = *(const bf16x8*)(&Wt[(col + 32) * WT_STRIDE + kb]);
        bf16x8 b3 = *(const bf16x8*)(&Wt[(col + 48) * WT_STRIDE + kb]);
        acc0 = __builtin_amdgcn_mfma_f32_16x16x32_bf16(a, b0, acc0, 0, 0, 0);
        acc1 = __builtin_amdgcn_mfma_f32_16x16x32_bf16(a, b1, acc1, 0, 0, 0);
        acc2 = __builtin_amdgcn_mfma_f32_16x16x32_bf16(a, b2, acc2, 0, 0, 0);
        acc3 = __builtin_amdgcn_mfma_f32_16x16x32_bf16(a, b3, acc3, 0, 0, 0);
    }

    // C/D layout: col = lane&15 (+16 per frag), row = (lane>>4)*4 + i
    int rr = row0 + (lane >> 4) * 4;
    for (int i = 0; i < 4; ++i) {
        int r = rr + i;
        if (r < N) {
            float* o = out + (size_t)r * OUT_CH;
            o[col]      = acc0[i];
            o[col + 16] = acc1[i];
            o[col + 32] = acc2[i];
            o[col + 48] = acc3[i];
        }
    }
}

// ---------------- CSR build --------------------------------------------------
__global__ __launch_bounds__(256) void hist_kernel(
    const int* __restrict__ rows, int* __restrict__ counts, int E)
{
    for (int e = blockIdx.x * blockDim.x + threadIdx.x; e < E;
         e += gridDim.x * blockDim.x) {
        atomicAdd(&counts[rows[e]], 1);
    }
}

__global__ __launch_bounds__(1024) void scan_kernel(
    const int* __restrict__ counts, int* __restrict__ offs,
    int* __restrict__ cursor, int n)
{
    __shared__ int lds[1024];
    const int t = threadIdx.x;
    const int chunk = (n + 1023) / 1024;
    const int base = t * chunk;

    int s = 0;
    for (int i = 0; i < chunk; ++i) {
        int j = base + i;
        if (j < n) s += counts[j];
    }
    lds[t] = s;
    __syncthreads();
    for (int ofs = 1; ofs < 1024; ofs <<= 1) {
        int v = 0;
        if (t >= ofs) v = lds[t - ofs];
        __syncthreads();
        if (t >= ofs) lds[t] += v;
        __syncthreads();
    }
    int run = lds[t] - s;  // exclusive prefix of this chunk
    for (int i = 0; i < chunk; ++i) {
        int j = base + i;
        if (j < n) {
            offs[j] = run;
            cursor[j] = run;
            run += counts[j];
        }
    }
    if (t == 1023) offs[n] = lds[1023];
}

__global__ __launch_bounds__(256) void scatter_kernel(
    const int* __restrict__ rows, const int* __restrict__ cols,
    const float* __restrict__ vals, int* __restrict__ cursor,
    int2* __restrict__ colval, int E)
{
    for (int e = blockIdx.x * blockDim.x + threadIdx.x; e < E;
         e += gridDim.x * blockDim.x) {
        int r = rows[e];
        int pos = atomicAdd(&cursor[r], 1);
        int2 cv;
        cv.x = cols[e];
        cv.y = __float_as_int(vals[e]);
        colval[pos] = cv;
    }
}

// ---------------- SpMM: one wave per output row ------------------------------
__global__ __launch_bounds__(256) void spmm_kernel(
    const int* __restrict__ offs, const int2* __restrict__ colval,
    const float* __restrict__ x, float* __restrict__ y,
    const float* __restrict__ bias, int N)
{
    const int lane = threadIdx.x & 63;
    int r = blockIdx.x * 4 + (threadIdx.x >> 6);
    if (r >= N) return;
    r = __builtin_amdgcn_readfirstlane(r);

    const int s = offs[r];
    const int e = offs[r + 1];
    float acc = 0.f;
    int i = s;
    for (; i + 4 <= e; i += 4) {
        int2 a0 = colval[i];
        int2 a1 = colval[i + 1];
        int2 a2 = colval[i + 2];
        int2 a3 = colval[i + 3];
        acc += __int_as_float(a0.y) * x[(size_t)a0.x * OUT_CH + lane];
        acc += __int_as_float(a1.y) * x[(size_t)a1.x * OUT_CH + lane];
        acc += __int_as_float(a2.y) * x[(size_t)a2.x * OUT_CH + lane];
        acc += __int_as_float(a3.y) * x[(size_t)a3.x * OUT_CH + lane];
    }
    for (; i < e; ++i) {
        int2 a = colval[i];
        acc += __int_as_float(a.y) * x[(size_t)a.x * OUT_CH + lane];
    }
    if (bias) acc += bias[lane];
    y[(size_t)r * OUT_CH + lane] = acc;
}

// ---------------- launch -----------------------------------------------------
static inline size_t align_up(size_t v) { return (v + 255) & ~(size_t)255; }

extern "C" void kernel_launch(void* const* d_in, const int* in_sizes, int n_in,
                              void* d_out, int out_size, void* d_ws, size_t ws_size,
                              hipStream_t stream)
{
    const int*   adj  = (const int*)d_in[0];    // [2,E] int32
    const float* vals = (const float*)d_in[1];  // [E]
    const float* feat = (const float*)d_in[2];  // [N,512]
    const float* Wm   = (const float*)d_in[3];  // [512,64]
    const float* bias = (const float*)d_in[4];  // [64]

    const int E = in_sizes[1];
    const int N = in_sizes[2] / IN_CH;
    const int* rows  = adj;
    const int* colsI = adj + E;

    char* w = (char*)d_ws;
    size_t o = 0;
    float* B0     = (float*)(w + o); o += align_up((size_t)N * OUT_CH * sizeof(float));
    int*   counts = (int*)  (w + o); o += align_up((size_t)N * sizeof(int));
    int*   offs   = (int*)  (w + o); o += align_up((size_t)(N + 1) * sizeof(int));
    int*   cursor = (int*)  (w + o); o += align_up((size_t)N * sizeof(int));
    int2*  colval = (int2*) (w + o); o += align_up((size_t)E * sizeof(int2));
    (void)ws_size; (void)n_in; (void)out_size;

    float* base = (float*)d_out;

    // 1. dense projection -> d_out
    gemm_kernel<<<(N + 63) / 64, 256, 0, stream>>>(feat, Wm, base, N);

    // 2. CSR build
    hipMemsetAsync(counts, 0, (size_t)N * sizeof(int), stream);
    hist_kernel<<<1024, 256, 0, stream>>>(rows, counts, E);
    scan_kernel<<<1, 1024, 0, stream>>>(counts, offs, cursor, N);
    scatter_kernel<<<1024, 256, 0, stream>>>(rows, colsI, vals, cursor, colval, E);

    // 3. two propagation rounds (bias fused into the last)
    spmm_kernel<<<(N + 3) / 4, 256, 0, stream>>>(offs, colval, base, B0, nullptr, N);
    spmm_kernel<<<(N + 3) / 4, 256, 0, stream>>>(offs, colval, B0, base, bias, N);
}